// Round 3
// baseline (127.895 us; speedup 1.0000x reference)
//
#include <hip/hip_runtime.h>
#include <hip/hip_bf16.h>

// SoftmaxLossRScore: mean(relu(logsumexp(A @ Neg^T, axis=1) - rowdot(A,P) + r + 1))
// B=2048, N=32768, D=128. bf16 MFMA fused GEMM+sumexp, no [B,N] materialization.
// A pre-scaled by log2(e) so epilogue is a bare v_exp_f32 (exp2).
// R3: 1D-over-N grid (256 blk x 128 cols): B tile read ONCE (8 MB total, was
// 64+ MB cross-XCD rereads), B frags register-resident, barrier-free A dbuf
// (each wave stages exactly the rows it consumes -> per-wave vmcnt(4), no
// __syncthreads in K-loop), LDS row-sum scratch (no in-loop atomics),
// finalize folded via last-block done-counter (one launch fewer).

#define B_ROWS 2048
#define N_NEG  32768
#define DIM    128
#define LOG2E  1.4426950408889634f
#define LN2    0.6931471805599453f
#define NBLK   256

typedef __bf16 bf16x8 __attribute__((ext_vector_type(8)));
typedef float  f32x4  __attribute__((ext_vector_type(4)));

static __device__ inline unsigned short f2bf(float f) {
    union { float f; unsigned u; } v; v.f = f;
    unsigned r = v.u + 0x7FFF + ((v.u >> 16) & 1);   // round-to-nearest-even
    return (unsigned short)(r >> 16);
}

static __device__ inline void load_lds16(const void* g, void* s) {
    __builtin_amdgcn_global_load_lds(
        (const __attribute__((address_space(1))) void*)g,
        (__attribute__((address_space(3))) void*)s,
        16, 0, 0);
}

// ---------- prep: anchor->bf16*log2e + pos_sim + zero sumexp/cnt, neg->bf16
__global__ void prep(const float* __restrict__ anchor,
                     const float* __restrict__ positive,
                     const float* __restrict__ neg,
                     unsigned short* __restrict__ a_bf,
                     unsigned short* __restrict__ n_bf,
                     float* __restrict__ pos_sim,
                     float* __restrict__ sumexp,
                     int* __restrict__ cnt) {
    int t = threadIdx.x;
    if (blockIdx.x < 256) {
        if (blockIdx.x == 0 && t == 0) *cnt = 0;
        int row = blockIdx.x * 8 + (t >> 5);
        int c4  = (t & 31) * 4;
        const float4 a4 = *(const float4*)(anchor   + row * DIM + c4);
        const float4 p4 = *(const float4*)(positive + row * DIM + c4);
        float dot = a4.x * p4.x + a4.y * p4.y + a4.z * p4.z + a4.w * p4.w;
        ushort4 ab;
        ab.x = f2bf(a4.x * LOG2E); ab.y = f2bf(a4.y * LOG2E);
        ab.z = f2bf(a4.z * LOG2E); ab.w = f2bf(a4.w * LOG2E);
        *(ushort4*)(a_bf + row * DIM + c4) = ab;
        #pragma unroll
        for (int m = 1; m <= 16; m <<= 1) dot += __shfl_xor(dot, m, 64);
        if ((t & 31) == 0) { pos_sim[row] = dot; sumexp[row] = 0.0f; }
    } else {
        int i = (blockIdx.x - 256) * 256 + t;   // float4 index
        #pragma unroll
        for (int k = 0; k < 4; k++) {
            int idx = i + k * (1024 * 256);
            float4 v = *(const float4*)(neg + (size_t)idx * 4);
            ushort4 o;
            o.x = f2bf(v.x); o.y = f2bf(v.y); o.z = f2bf(v.z); o.w = f2bf(v.w);
            *(ushort4*)(n_bf + (size_t)idx * 4) = o;
        }
    }
}

// ---------- main: fused bf16 GEMM + sum(exp2) + folded finalize -------------
// 256 blocks x 512 thr (8 waves). Block owns cols [bid*128, +128).
// LDS: B 32K + A dbuf 64K + rowsum 8K = 104 KB -> 1 block/CU, 2 waves/SIMD.
// LDS rows 256 B, chunk slot j of row r holds global chunk j^(r&7) (R2 swizzle).
__global__ __launch_bounds__(512, 2) void fused_gemm_lse(
        const unsigned short* __restrict__ A,
        const unsigned short* __restrict__ Nb,
        float* __restrict__ sumexp,
        const float* __restrict__ pos_sim,
        const float* __restrict__ r_score,
        int* __restrict__ cnt,
        float* __restrict__ out) {
    __shared__ unsigned short ldsB[128 * 128];       // 32 KB, static
    __shared__ unsigned short ldsA[2][128 * 128];    // 64 KB, dbuf
    __shared__ float sumLDS[B_ROWS];                 // 8 KB
    __shared__ float red[8];
    __shared__ int isLast;

    const int tid  = threadIdx.x;
    const int wave = tid >> 6, lane = tid & 63;
    const int q = lane >> 4, c = lane & 15;          // q=row-quad, c=col-lane
    const int lrow = q, lchk = c;                    // staging aliases
    const int bid  = blockIdx.x;

    // ---- initial stage: B cols (bid*128..+128) + A tile 0; wave-private rows
    const unsigned short* Bg = Nb + (size_t)bid * 128 * DIM;
    #pragma unroll
    for (int i = 0; i < 4; i++) {
        int off = wave * 2048 + i * 512;             // 4 rows per group
        int r   = (off >> 7) + lrow;
        int gofs = r * DIM + ((lchk ^ (r & 7)) << 3);
        load_lds16(Bg + gofs, &ldsB[off]);
        load_lds16(A  + gofs, &ldsA[0][off]);
    }
    asm volatile("s_waitcnt vmcnt(0)" ::: "memory");
    __syncthreads();                                  // B visible to all waves

    int swz[4];
    #pragma unroll
    for (int k = 0; k < 4; k++) swz[k] = (((k * 4 + q) ^ (c & 7)) << 3);

    // ---- B fragments register-resident: 8 col-subtiles x 4 k-steps
    bf16x8 bfr[8][4];
    #pragma unroll
    for (int j = 0; j < 8; j++)
        #pragma unroll
        for (int k = 0; k < 4; k++)
            bfr[j][k] = *(const bf16x8*)&ldsB[(j * 16 + c) * DIM + swz[k]];

    const f32x4 zero4 = {0.f, 0.f, 0.f, 0.f};
    const int arow = wave * 16 + c;                   // wave-private A row

    for (int t = 0; t < 16; t++) {
        const unsigned short* ldsCur = ldsA[t & 1];
        if (t < 15) {                                 // prefetch A(t+1), own rows
            const unsigned short* Ag = A + (size_t)(t + 1) * 128 * DIM;
            unsigned short* dst = &ldsA[(t + 1) & 1][0];
            #pragma unroll
            for (int i = 0; i < 4; i++) {
                int off = wave * 2048 + i * 512;
                int r   = (off >> 7) + lrow;
                int gofs = r * DIM + ((lchk ^ (r & 7)) << 3);
                load_lds16(Ag + gofs, dst + off);
            }
            asm volatile("s_waitcnt vmcnt(4)" ::: "memory");  // stage(t) done
        } else {
            asm volatile("s_waitcnt vmcnt(0)" ::: "memory");
        }

        bf16x8 af[4];
        #pragma unroll
        for (int k = 0; k < 4; k++)
            af[k] = *(const bf16x8*)&ldsCur[arow * DIM + swz[k]];

        f32x4 sum4 = zero4;
        #pragma unroll
        for (int j = 0; j < 8; j++) {
            f32x4 acc = __builtin_amdgcn_mfma_f32_16x16x32_bf16(af[0], bfr[j][0], zero4, 0, 0, 0);
            acc = __builtin_amdgcn_mfma_f32_16x16x32_bf16(af[1], bfr[j][1], acc, 0, 0, 0);
            acc = __builtin_amdgcn_mfma_f32_16x16x32_bf16(af[2], bfr[j][2], acc, 0, 0, 0);
            acc = __builtin_amdgcn_mfma_f32_16x16x32_bf16(af[3], bfr[j][3], acc, 0, 0, 0);
            sum4[0] += __builtin_amdgcn_exp2f(acc[0]);
            sum4[1] += __builtin_amdgcn_exp2f(acc[1]);
            sum4[2] += __builtin_amdgcn_exp2f(acc[2]);
            sum4[3] += __builtin_amdgcn_exp2f(acc[3]);
        }
        // reduce over the 16 col-lanes; (wave,t) owns disjoint rows -> plain write
        float v0 = sum4[0], v1 = sum4[1], v2 = sum4[2], v3 = sum4[3];
        #pragma unroll
        for (int m = 1; m <= 8; m <<= 1) {
            v0 += __shfl_xor(v0, m, 64);
            v1 += __shfl_xor(v1, m, 64);
            v2 += __shfl_xor(v2, m, 64);
            v3 += __shfl_xor(v3, m, 64);
        }
        if ((lane & 15) == 0) {
            f32x4 w = {v0, v1, v2, v3};
            *(f32x4*)&sumLDS[t * 128 + wave * 16 + q * 4] = w;
        }
    }
    __syncthreads();

    // ---- flush block-local row sums (one atomic per row per block)
    #pragma unroll
    for (int i = 0; i < 4; i++) {
        int row = tid + i * 512;
        atomicAdd(&sumexp[row], sumLDS[row]);
    }
    __threadfence();
    __syncthreads();
    if (tid == 0) isLast = (atomicAdd(cnt, 1) == NBLK - 1);
    __syncthreads();
    if (!isLast) return;

    // ---- folded finalize (last block): lse, relu, mean
    float acc = 0.0f;
    #pragma unroll
    for (int i = 0; i < 4; i++) {
        int row = tid + i * 512;
        float se   = atomicAdd(&sumexp[row], 0.0f);   // coherent cross-XCD read
        float loss = __log2f(se) * LN2 - pos_sim[row] + r_score[row] + 1.0f;
        acc += fmaxf(loss, 0.0f);
    }
    #pragma unroll
    for (int m = 1; m <= 32; m <<= 1) acc += __shfl_xor(acc, m, 64);
    if (lane == 0) red[wave] = acc;
    __syncthreads();
    if (tid == 0) {
        float s = 0.0f;
        #pragma unroll
        for (int w = 0; w < 8; w++) s += red[w];
        out[0] = s * (1.0f / (float)B_ROWS);
    }
}

extern "C" void kernel_launch(void* const* d_in, const int* in_sizes, int n_in,
                              void* d_out, int out_size, void* d_ws, size_t ws_size,
                              hipStream_t stream) {
    const float* anchor   = (const float*)d_in[0];
    const float* positive = (const float*)d_in[1];
    const float* negative = (const float*)d_in[2];
    const float* r_score  = (const float*)d_in[3];
    float* out = (float*)d_out;

    char* ws = (char*)d_ws;
    float* sumexp        = (float*)ws;                            // 8 KB
    float* pos_sim       = (float*)(ws + 8192);                   // 8 KB
    int*   cnt           = (int*)(ws + 16384);                    // 4 B
    unsigned short* a_bf = (unsigned short*)(ws + 32768);         // 512 KB
    unsigned short* n_bf = (unsigned short*)(ws + 32768 + 524288);// 8 MB

    prep<<<1280, 256, 0, stream>>>(anchor, positive, negative, a_bf, n_bf,
                                   pos_sim, sumexp, cnt);
    fused_gemm_lse<<<NBLK, 512, 0, stream>>>(a_bf, n_bf, sumexp, pos_sim,
                                             r_score, cnt, out);
}

// Round 4
// 124.870 us; speedup vs baseline: 1.0242x; 1.0242x over previous
//
#include <hip/hip_runtime.h>
#include <hip/hip_bf16.h>

// SoftmaxLossRScore: mean(relu(logsumexp(A @ Neg^T, axis=1) - rowdot(A,P) + r + 1))
// B=2048, N=32768, D=128. bf16 MFMA fused GEMM+sumexp, no [B,N] materialization.
// A pre-scaled by log2(e) so epilogue is a bare v_exp_f32 (exp2).
// R4: zero-LDS register GEMM. R3 post-mortem: asm memory clobbers forced LDS
// re-reads of B frags every iter (VGPR=104 proved non-residency) + 524K-atomic
// tail. Now: B frags gathered once from global (L2-hot) into regs, A frags
// gathered per t-step (4 dwordx4), no LDS staging, no barriers in loop, no
// atomics in GEMM -- coalesced f32x4 partial stores + small reduce kernel.

#define B_ROWS 2048
#define N_NEG  32768
#define DIM    128
#define LOG2E  1.4426950408889634f
#define LN2    0.6931471805599453f

typedef __bf16 bf16x8 __attribute__((ext_vector_type(8)));
typedef float  f32x4  __attribute__((ext_vector_type(4)));

static __device__ inline unsigned short f2bf(float f) {
    union { float f; unsigned u; } v; v.f = f;
    unsigned r = v.u + 0x7FFF + ((v.u >> 16) & 1);   // round-to-nearest-even
    return (unsigned short)(r >> 16);
}

// ---------- prep: anchor->bf16*log2e + pos_sim, neg->bf16, zero out ---------
__global__ void prep(const float* __restrict__ anchor,
                     const float* __restrict__ positive,
                     const float* __restrict__ neg,
                     unsigned short* __restrict__ a_bf,
                     unsigned short* __restrict__ n_bf,
                     float* __restrict__ pos_sim,
                     float* __restrict__ out) {
    int t = threadIdx.x;
    if (blockIdx.x < 256) {
        if (blockIdx.x == 0 && t == 0) out[0] = 0.0f;
        int row = blockIdx.x * 8 + (t >> 5);
        int c4  = (t & 31) * 4;
        const float4 a4 = *(const float4*)(anchor   + row * DIM + c4);
        const float4 p4 = *(const float4*)(positive + row * DIM + c4);
        float dot = a4.x * p4.x + a4.y * p4.y + a4.z * p4.z + a4.w * p4.w;
        ushort4 ab;
        ab.x = f2bf(a4.x * LOG2E); ab.y = f2bf(a4.y * LOG2E);
        ab.z = f2bf(a4.z * LOG2E); ab.w = f2bf(a4.w * LOG2E);
        *(ushort4*)(a_bf + row * DIM + c4) = ab;
        #pragma unroll
        for (int m = 1; m <= 16; m <<= 1) dot += __shfl_xor(dot, m, 64);
        if ((t & 31) == 0) pos_sim[row] = dot;
    } else {
        int i = (blockIdx.x - 256) * 256 + t;   // float4 index
        #pragma unroll
        for (int k = 0; k < 4; k++) {
            int idx = i + k * (1024 * 256);
            float4 v = *(const float4*)(neg + (size_t)idx * 4);
            ushort4 o;
            o.x = f2bf(v.x); o.y = f2bf(v.y); o.z = f2bf(v.z); o.w = f2bf(v.w);
            *(ushort4*)(n_bf + (size_t)idx * 4) = o;
        }
    }
}

// ---------- main: register-only fused bf16 GEMM + sum(exp2) -----------------
// Grid 1024 = 512 col-chunks (64 cols) x 2 row-halves (1024 rows).
// Block 256 thr = 4 waves; wave w handles rows t*64+w*16..+16 per t-step.
// B frags (64x128) register-resident per wave; A frags gathered per t.
// partial[cid*2048 + grow]: coalesced f32x4 stores, no atomics.
__global__ __launch_bounds__(256, 3) void fused_gemm_lse(
        const unsigned short* __restrict__ A,
        const unsigned short* __restrict__ Nb,
        float* __restrict__ partial) {
    __shared__ float sumLDS[1024];

    const int tid  = threadIdx.x;
    const int wave = tid >> 6, lane = tid & 63;
    const int q = lane >> 4, c = lane & 15;
    const int cid  = blockIdx.x >> 1;      // 0..511: 64-col chunk
    const int half = blockIdx.x & 1;       // 0..1:   1024-row half

    // B fragments: 64 cols x 128 k, gathered once (L2-hot), register resident
    bf16x8 bfr[4][4];
    const unsigned short* Bb = Nb + (size_t)cid * 64 * DIM;
    #pragma unroll
    for (int j = 0; j < 4; j++)
        #pragma unroll
        for (int k = 0; k < 4; k++)
            bfr[j][k] = *(const bf16x8*)(Bb + (j * 16 + c) * DIM + k * 32 + q * 8);

    const unsigned short* Ab = A + ((size_t)half * 1024 + wave * 16 + c) * DIM + q * 8;
    const f32x4 zero4 = {0.f, 0.f, 0.f, 0.f};

    for (int t = 0; t < 16; t++) {
        const unsigned short* Ar = Ab + t * 64 * DIM;
        bf16x8 af[4];
        #pragma unroll
        for (int k = 0; k < 4; k++)
            af[k] = *(const bf16x8*)(Ar + k * 32);

        f32x4 sum4 = zero4;
        #pragma unroll
        for (int j = 0; j < 4; j++) {
            f32x4 acc = __builtin_amdgcn_mfma_f32_16x16x32_bf16(af[0], bfr[j][0], zero4, 0, 0, 0);
            acc = __builtin_amdgcn_mfma_f32_16x16x32_bf16(af[1], bfr[j][1], acc, 0, 0, 0);
            acc = __builtin_amdgcn_mfma_f32_16x16x32_bf16(af[2], bfr[j][2], acc, 0, 0, 0);
            acc = __builtin_amdgcn_mfma_f32_16x16x32_bf16(af[3], bfr[j][3], acc, 0, 0, 0);
            sum4[0] += __builtin_amdgcn_exp2f(acc[0]);
            sum4[1] += __builtin_amdgcn_exp2f(acc[1]);
            sum4[2] += __builtin_amdgcn_exp2f(acc[2]);
            sum4[3] += __builtin_amdgcn_exp2f(acc[3]);
        }
        // reduce over the 16 col-lanes; (wave,t,q) rows are disjoint
        float v0 = sum4[0], v1 = sum4[1], v2 = sum4[2], v3 = sum4[3];
        #pragma unroll
        for (int m = 1; m <= 8; m <<= 1) {
            v0 += __shfl_xor(v0, m, 64);
            v1 += __shfl_xor(v1, m, 64);
            v2 += __shfl_xor(v2, m, 64);
            v3 += __shfl_xor(v3, m, 64);
        }
        if (c == 0) {
            f32x4 w = {v0, v1, v2, v3};
            *(f32x4*)&sumLDS[t * 64 + wave * 16 + q * 4] = w;
        }
    }
    __syncthreads();
    // coalesced flush: block's 1024 row-partials, f32x4 per thread
    f32x4 p = *(const f32x4*)&sumLDS[tid * 4];
    *(f32x4*)&partial[(size_t)cid * 2048 + half * 1024 + tid * 4] = p;
}

// ---------- finalize: sum 512 partials/row, lse, relu, mean -----------------
// 32 blocks x 256 thr (4 waves). Block handles rows [bid*64, +64); wave w
// sums cid-range [w*128, +128) (coalesced 64-lane dword loads), cross-wave
// combine in LDS, then loss + block reduce + atomicAdd.
__global__ void finalize(const float* __restrict__ partial,
                         const float* __restrict__ pos_sim,
                         const float* __restrict__ r_score,
                         float* __restrict__ out) {
    __shared__ float red[4][64];
    const int tid  = threadIdx.x;
    const int wave = tid >> 6, lane = tid & 63;
    const int rowb = blockIdx.x * 64;

    float se = 0.0f;
    #pragma unroll 4
    for (int i = 0; i < 128; i++) {
        int cid = wave * 128 + i;
        se += partial[(size_t)cid * 2048 + rowb + lane];
    }
    red[wave][lane] = se;
    __syncthreads();

    if (wave == 0) {
        float tot = red[0][lane] + red[1][lane] + red[2][lane] + red[3][lane];
        int row = rowb + lane;
        float loss = __log2f(tot) * LN2 - pos_sim[row] + r_score[row] + 1.0f;
        float acc = fmaxf(loss, 0.0f);
        #pragma unroll
        for (int m = 1; m <= 32; m <<= 1) acc += __shfl_xor(acc, m, 64);
        if (lane == 0) atomicAdd(out, acc * (1.0f / (float)B_ROWS));
    }
}

extern "C" void kernel_launch(void* const* d_in, const int* in_sizes, int n_in,
                              void* d_out, int out_size, void* d_ws, size_t ws_size,
                              hipStream_t stream) {
    const float* anchor   = (const float*)d_in[0];
    const float* positive = (const float*)d_in[1];
    const float* negative = (const float*)d_in[2];
    const float* r_score  = (const float*)d_in[3];
    float* out = (float*)d_out;

    char* ws = (char*)d_ws;
    float* pos_sim       = (float*)ws;                              // 8 KB
    float* partial       = (float*)(ws + 8192);                     // 4 MB (512x2048)
    unsigned short* a_bf = (unsigned short*)(ws + 8192 + 4194304);  // 512 KB
    unsigned short* n_bf = (unsigned short*)(ws + 8192 + 4194304 + 524288); // 8 MB

    prep<<<1280, 256, 0, stream>>>(anchor, positive, negative, a_bf, n_bf,
                                   pos_sim, out);
    fused_gemm_lse<<<1024, 256, 0, stream>>>(a_bf, n_bf, partial);
    finalize<<<32, 256, 0, stream>>>(partial, pos_sim, r_score, out);
}

// Round 5
// 123.615 us; speedup vs baseline: 1.0346x; 1.0102x over previous
//
#include <hip/hip_runtime.h>
#include <hip/hip_bf16.h>

// SoftmaxLossRScore: mean(relu(logsumexp(A @ Neg^T, axis=1) - rowdot(A,P) + r + 1))
// B=2048, N=32768, D=128. bf16 MFMA fused GEMM+sumexp, no [B,N] materialization.
// A pre-scaled by log2(e) so epilogue is a bare v_exp_f32 (exp2).
// R5: R4 + asm register pin on the B fragments. R4 post-mortem: VGPR=52 proved
// LLVM rematerialized the loop-invariant B-frag loads every t-step -> 1.3 GB
// of L2 re-reads = the 44us. Empty asm "+v" makes the values opaque so the
// allocator must keep all 16 frags (64 VGPRs) live across the loop.

#define B_ROWS 2048
#define N_NEG  32768
#define DIM    128
#define LOG2E  1.4426950408889634f
#define LN2    0.6931471805599453f

typedef __bf16 bf16x8 __attribute__((ext_vector_type(8)));
typedef float  f32x4  __attribute__((ext_vector_type(4)));

static __device__ inline unsigned short f2bf(float f) {
    union { float f; unsigned u; } v; v.f = f;
    unsigned r = v.u + 0x7FFF + ((v.u >> 16) & 1);   // round-to-nearest-even
    return (unsigned short)(r >> 16);
}

// opaque register barrier: forbids rematerialization of the producing load
static __device__ inline void pin(bf16x8& v) {
    f32x4 t = __builtin_bit_cast(f32x4, v);
    asm volatile("" : "+v"(t));
    v = __builtin_bit_cast(bf16x8, t);
}

// ---------- prep: anchor->bf16*log2e + pos_sim, neg->bf16, zero out ---------
__global__ void prep(const float* __restrict__ anchor,
                     const float* __restrict__ positive,
                     const float* __restrict__ neg,
                     unsigned short* __restrict__ a_bf,
                     unsigned short* __restrict__ n_bf,
                     float* __restrict__ pos_sim,
                     float* __restrict__ out) {
    int t = threadIdx.x;
    if (blockIdx.x < 256) {
        if (blockIdx.x == 0 && t == 0) out[0] = 0.0f;
        int row = blockIdx.x * 8 + (t >> 5);
        int c4  = (t & 31) * 4;
        const float4 a4 = *(const float4*)(anchor   + row * DIM + c4);
        const float4 p4 = *(const float4*)(positive + row * DIM + c4);
        float dot = a4.x * p4.x + a4.y * p4.y + a4.z * p4.z + a4.w * p4.w;
        ushort4 ab;
        ab.x = f2bf(a4.x * LOG2E); ab.y = f2bf(a4.y * LOG2E);
        ab.z = f2bf(a4.z * LOG2E); ab.w = f2bf(a4.w * LOG2E);
        *(ushort4*)(a_bf + row * DIM + c4) = ab;
        #pragma unroll
        for (int m = 1; m <= 16; m <<= 1) dot += __shfl_xor(dot, m, 64);
        if ((t & 31) == 0) pos_sim[row] = dot;
    } else {
        int i = (blockIdx.x - 256) * 256 + t;   // float4 index
        #pragma unroll
        for (int k = 0; k < 4; k++) {
            int idx = i + k * (1024 * 256);
            float4 v = *(const float4*)(neg + (size_t)idx * 4);
            ushort4 o;
            o.x = f2bf(v.x); o.y = f2bf(v.y); o.z = f2bf(v.z); o.w = f2bf(v.w);
            *(ushort4*)(n_bf + (size_t)idx * 4) = o;
        }
    }
}

// ---------- main: register-only fused bf16 GEMM + sum(exp2) -----------------
// Grid 1024 = 512 col-chunks (64 cols) x 2 row-halves (1024 rows).
// Block 256 thr = 4 waves; wave w handles rows t*64+w*16..+16 per t-step.
// B frags (64x128) PINNED register-resident per wave; A frags gathered per t.
// partial[cid*2048 + grow]: coalesced f32x4 stores, no atomics.
__global__ __launch_bounds__(256, 3) void fused_gemm_lse(
        const unsigned short* __restrict__ A,
        const unsigned short* __restrict__ Nb,
        float* __restrict__ partial) {
    __shared__ float sumLDS[1024];

    const int tid  = threadIdx.x;
    const int wave = tid >> 6, lane = tid & 63;
    const int q = lane >> 4, c = lane & 15;
    const int cid  = blockIdx.x >> 1;      // 0..511: 64-col chunk
    const int half = blockIdx.x & 1;       // 0..1:   1024-row half

    // B fragments: 64 cols x 128 k, gathered once (L2-hot), pinned in VGPRs
    bf16x8 bfr[4][4];
    const unsigned short* Bb = Nb + (size_t)cid * 64 * DIM;
    #pragma unroll
    for (int j = 0; j < 4; j++)
        #pragma unroll
        for (int k = 0; k < 4; k++)
            bfr[j][k] = *(const bf16x8*)(Bb + (j * 16 + c) * DIM + k * 32 + q * 8);
    #pragma unroll
    for (int j = 0; j < 4; j++)
        #pragma unroll
        for (int k = 0; k < 4; k++)
            pin(bfr[j][k]);

    const unsigned short* Ab = A + ((size_t)half * 1024 + wave * 16 + c) * DIM + q * 8;
    const f32x4 zero4 = {0.f, 0.f, 0.f, 0.f};

    for (int t = 0; t < 16; t++) {
        const unsigned short* Ar = Ab + t * 64 * DIM;
        bf16x8 af[4];
        #pragma unroll
        for (int k = 0; k < 4; k++)
            af[k] = *(const bf16x8*)(Ar + k * 32);

        f32x4 sum4 = zero4;
        #pragma unroll
        for (int j = 0; j < 4; j++) {
            f32x4 acc = __builtin_amdgcn_mfma_f32_16x16x32_bf16(af[0], bfr[j][0], zero4, 0, 0, 0);
            acc = __builtin_amdgcn_mfma_f32_16x16x32_bf16(af[1], bfr[j][1], acc, 0, 0, 0);
            acc = __builtin_amdgcn_mfma_f32_16x16x32_bf16(af[2], bfr[j][2], acc, 0, 0, 0);
            acc = __builtin_amdgcn_mfma_f32_16x16x32_bf16(af[3], bfr[j][3], acc, 0, 0, 0);
            sum4[0] += __builtin_amdgcn_exp2f(acc[0]);
            sum4[1] += __builtin_amdgcn_exp2f(acc[1]);
            sum4[2] += __builtin_amdgcn_exp2f(acc[2]);
            sum4[3] += __builtin_amdgcn_exp2f(acc[3]);
        }
        // reduce over the 16 col-lanes; (wave,t,q) rows are disjoint
        float v0 = sum4[0], v1 = sum4[1], v2 = sum4[2], v3 = sum4[3];
        #pragma unroll
        for (int m = 1; m <= 8; m <<= 1) {
            v0 += __shfl_xor(v0, m, 64);
            v1 += __shfl_xor(v1, m, 64);
            v2 += __shfl_xor(v2, m, 64);
            v3 += __shfl_xor(v3, m, 64);
        }
        if (c == 0) {
            f32x4 w = {v0, v1, v2, v3};
            *(f32x4*)&sumLDS[t * 64 + wave * 16 + q * 4] = w;
        }
    }
    __syncthreads();
    // coalesced flush: block's 1024 row-partials, f32x4 per thread
    f32x4 p = *(const f32x4*)&sumLDS[tid * 4];
    *(f32x4*)&partial[(size_t)cid * 2048 + half * 1024 + tid * 4] = p;
}

// ---------- finalize: sum 512 partials/row, lse, relu, mean -----------------
__global__ void finalize(const float* __restrict__ partial,
                         const float* __restrict__ pos_sim,
                         const float* __restrict__ r_score,
                         float* __restrict__ out) {
    __shared__ float red[4][64];
    const int tid  = threadIdx.x;
    const int wave = tid >> 6, lane = tid & 63;
    const int rowb = blockIdx.x * 64;

    float se = 0.0f;
    #pragma unroll 4
    for (int i = 0; i < 128; i++) {
        int cid = wave * 128 + i;
        se += partial[(size_t)cid * 2048 + rowb + lane];
    }
    red[wave][lane] = se;
    __syncthreads();

    if (wave == 0) {
        float tot = red[0][lane] + red[1][lane] + red[2][lane] + red[3][lane];
        int row = rowb + lane;
        float loss = __log2f(tot) * LN2 - pos_sim[row] + r_score[row] + 1.0f;
        float acc = fmaxf(loss, 0.0f);
        #pragma unroll
        for (int m = 1; m <= 32; m <<= 1) acc += __shfl_xor(acc, m, 64);
        if (lane == 0) atomicAdd(out, acc * (1.0f / (float)B_ROWS));
    }
}

extern "C" void kernel_launch(void* const* d_in, const int* in_sizes, int n_in,
                              void* d_out, int out_size, void* d_ws, size_t ws_size,
                              hipStream_t stream) {
    const float* anchor   = (const float*)d_in[0];
    const float* positive = (const float*)d_in[1];
    const float* negative = (const float*)d_in[2];
    const float* r_score  = (const float*)d_in[3];
    float* out = (float*)d_out;

    char* ws = (char*)d_ws;
    float* pos_sim       = (float*)ws;                              // 8 KB
    float* partial       = (float*)(ws + 8192);                     // 4 MB (512x2048)
    unsigned short* a_bf = (unsigned short*)(ws + 8192 + 4194304);  // 512 KB
    unsigned short* n_bf = (unsigned short*)(ws + 8192 + 4194304 + 524288); // 8 MB

    prep<<<1280, 256, 0, stream>>>(anchor, positive, negative, a_bf, n_bf,
                                   pos_sim, out);
    fused_gemm_lse<<<1024, 256, 0, stream>>>(a_bf, n_bf, partial);
    finalize<<<32, 256, 0, stream>>>(partial, pos_sim, r_score, out);
}

// Round 6
// 109.994 us; speedup vs baseline: 1.1627x; 1.1238x over previous
//
#include <hip/hip_runtime.h>
#include <hip/hip_bf16.h>

// SoftmaxLossRScore: mean(relu(logsumexp(A @ Neg^T, axis=1) - rowdot(A,P) + r + 1))
// B=2048, N=32768, D=128. bf16 MFMA fused GEMM+sumexp, no [B,N] materialization.
// A pre-scaled by log2(e) so epilogue is a bare v_exp_f32 (exp2).
// R6: A-resident / B-streamed. Wave holds 64 A-rows x K=128 pinned (64 VGPR);
// C-layout rows == A rows, so row-sums accumulate per-lane in registers ->
// ZERO shuffles/LDS in the K-loop (R5 had 256 ds_swizzle/wave). Grid 512 =
// rg(32) x cc(16), cc = bid&15 -> XCD = cc%8: each XCD streams only 2
// col-chunks of B (1 MB, L2-resident) -> B re-reads are L2-local.

#define B_ROWS 2048
#define N_NEG  32768
#define DIM    128
#define LOG2E  1.4426950408889634f
#define LN2    0.6931471805599453f

typedef __bf16 bf16x8 __attribute__((ext_vector_type(8)));
typedef float  f32x4  __attribute__((ext_vector_type(4)));

static __device__ inline unsigned short f2bf(float f) {
    union { float f; unsigned u; } v; v.f = f;
    unsigned r = v.u + 0x7FFF + ((v.u >> 16) & 1);   // round-to-nearest-even
    return (unsigned short)(r >> 16);
}

// opaque register barrier: forbids rematerialization of the producing load
static __device__ inline void pin(bf16x8& v) {
    f32x4 t = __builtin_bit_cast(f32x4, v);
    asm volatile("" : "+v"(t));
    v = __builtin_bit_cast(bf16x8, t);
}

// ---------- prep: anchor->bf16*log2e + pos_sim, neg->bf16, zero out ---------
__global__ void prep(const float* __restrict__ anchor,
                     const float* __restrict__ positive,
                     const float* __restrict__ neg,
                     unsigned short* __restrict__ a_bf,
                     unsigned short* __restrict__ n_bf,
                     float* __restrict__ pos_sim,
                     float* __restrict__ out) {
    int t = threadIdx.x;
    if (blockIdx.x < 256) {
        if (blockIdx.x == 0 && t == 0) out[0] = 0.0f;
        int row = blockIdx.x * 8 + (t >> 5);
        int c4  = (t & 31) * 4;
        const float4 a4 = *(const float4*)(anchor   + row * DIM + c4);
        const float4 p4 = *(const float4*)(positive + row * DIM + c4);
        float dot = a4.x * p4.x + a4.y * p4.y + a4.z * p4.z + a4.w * p4.w;
        ushort4 ab;
        ab.x = f2bf(a4.x * LOG2E); ab.y = f2bf(a4.y * LOG2E);
        ab.z = f2bf(a4.z * LOG2E); ab.w = f2bf(a4.w * LOG2E);
        *(ushort4*)(a_bf + row * DIM + c4) = ab;
        #pragma unroll
        for (int m = 1; m <= 16; m <<= 1) dot += __shfl_xor(dot, m, 64);
        if ((t & 31) == 0) pos_sim[row] = dot;
    } else {
        int i = (blockIdx.x - 256) * 256 + t;   // float4 index
        #pragma unroll
        for (int k = 0; k < 4; k++) {
            int idx = i + k * (1024 * 256);
            float4 v = *(const float4*)(neg + (size_t)idx * 4);
            ushort4 o;
            o.x = f2bf(v.x); o.y = f2bf(v.y); o.z = f2bf(v.z); o.w = f2bf(v.w);
            *(ushort4*)(n_bf + (size_t)idx * 4) = o;
        }
    }
}

// ---------- main: A-resident fused bf16 GEMM + sum(exp2) --------------------
// Grid 512 = rowgroup (64 rows) x colchunk (2048 cols), cc-major for XCD-local
// B. Block 256 thr = 4 waves; all waves share the 64 rows, split cols 4x512.
// Per col-tile (16 cols): 4 B-frag loads, 16 MFMA (4 indep chains), 16 exp,
// 16 adds. Row-sums live in sumacc registers; one shuffle-reduce at the end.
// partial[cc*2048 + row]: one plain store per block, no atomics.
__global__ __launch_bounds__(256, 2) void fused_gemm_lse(
        const unsigned short* __restrict__ A,
        const unsigned short* __restrict__ Nb,
        float* __restrict__ partial) {
    __shared__ float sLDS[4][64];

    const int tid  = threadIdx.x;
    const int wave = tid >> 6, lane = tid & 63;
    const int q = lane >> 4, c = lane & 15;
    const int cc = blockIdx.x & 15;        // col-chunk -> XCD = cc % 8
    const int rg = blockIdx.x >> 4;        // row-group (64 rows)

    // A fragments: 64 rows x 128 k, gathered once (L2-hot), pinned (64 VGPRs)
    bf16x8 af[4][4];
    const unsigned short* Ab = A + (size_t)rg * 64 * DIM;
    #pragma unroll
    for (int i = 0; i < 4; i++)
        #pragma unroll
        for (int k = 0; k < 4; k++)
            af[i][k] = *(const bf16x8*)(Ab + (i * 16 + c) * DIM + k * 32 + q * 8);
    #pragma unroll
    for (int i = 0; i < 4; i++)
        #pragma unroll
        for (int k = 0; k < 4; k++)
            pin(af[i][k]);

    const unsigned short* Bb = Nb + ((size_t)cc * 2048 + wave * 512 + c) * DIM + q * 8;
    const f32x4 zero4 = {0.f, 0.f, 0.f, 0.f};
    f32x4 sumacc[4] = {zero4, zero4, zero4, zero4};

    #pragma unroll 2
    for (int ct = 0; ct < 32; ct++) {
        const unsigned short* Bt = Bb + ct * 16 * DIM;
        bf16x8 bf[4];
        #pragma unroll
        for (int k = 0; k < 4; k++)
            bf[k] = *(const bf16x8*)(Bt + k * 32);
        #pragma unroll
        for (int i = 0; i < 4; i++) {
            f32x4 acc = __builtin_amdgcn_mfma_f32_16x16x32_bf16(af[i][0], bf[0], zero4, 0, 0, 0);
            acc = __builtin_amdgcn_mfma_f32_16x16x32_bf16(af[i][1], bf[1], acc, 0, 0, 0);
            acc = __builtin_amdgcn_mfma_f32_16x16x32_bf16(af[i][2], bf[2], acc, 0, 0, 0);
            acc = __builtin_amdgcn_mfma_f32_16x16x32_bf16(af[i][3], bf[3], acc, 0, 0, 0);
            sumacc[i][0] += __builtin_amdgcn_exp2f(acc[0]);
            sumacc[i][1] += __builtin_amdgcn_exp2f(acc[1]);
            sumacc[i][2] += __builtin_amdgcn_exp2f(acc[2]);
            sumacc[i][3] += __builtin_amdgcn_exp2f(acc[3]);
        }
    }

    // one-time reduce over the 16 col-lanes (C cols = streamed B cols)
    #pragma unroll
    for (int i = 0; i < 4; i++) {
        #pragma unroll
        for (int r = 0; r < 4; r++) {
            float v = sumacc[i][r];
            v += __shfl_xor(v, 1, 64);
            v += __shfl_xor(v, 2, 64);
            v += __shfl_xor(v, 4, 64);
            v += __shfl_xor(v, 8, 64);
            sumacc[i][r] = v;
        }
        if (c == 0)
            *(f32x4*)&sLDS[wave][i * 16 + q * 4] = sumacc[i];
    }
    __syncthreads();
    if (tid < 64) {
        float s = sLDS[0][tid] + sLDS[1][tid] + sLDS[2][tid] + sLDS[3][tid];
        partial[cc * 2048 + rg * 64 + tid] = s;
    }
}

// ---------- finalize: sum 16 partials/row, lse, relu, mean ------------------
__global__ void finalize(const float* __restrict__ partial,
                         const float* __restrict__ pos_sim,
                         const float* __restrict__ r_score,
                         float* __restrict__ out) {
    __shared__ float red[4];
    const int tid  = threadIdx.x;
    const int wave = tid >> 6, lane = tid & 63;
    const int row  = blockIdx.x * 256 + tid;

    float se = 0.0f;
    #pragma unroll
    for (int ccp = 0; ccp < 16; ccp++)
        se += partial[ccp * 2048 + row];
    float loss = __log2f(se) * LN2 - pos_sim[row] + r_score[row] + 1.0f;
    float acc  = fmaxf(loss, 0.0f);
    #pragma unroll
    for (int m = 1; m <= 32; m <<= 1) acc += __shfl_xor(acc, m, 64);
    if (lane == 0) red[wave] = acc;
    __syncthreads();
    if (tid == 0)
        atomicAdd(out, (red[0] + red[1] + red[2] + red[3]) * (1.0f / (float)B_ROWS));
}

extern "C" void kernel_launch(void* const* d_in, const int* in_sizes, int n_in,
                              void* d_out, int out_size, void* d_ws, size_t ws_size,
                              hipStream_t stream) {
    const float* anchor   = (const float*)d_in[0];
    const float* positive = (const float*)d_in[1];
    const float* negative = (const float*)d_in[2];
    const float* r_score  = (const float*)d_in[3];
    float* out = (float*)d_out;

    char* ws = (char*)d_ws;
    float* pos_sim       = (float*)ws;                              // 8 KB
    float* partial       = (float*)(ws + 8192);                     // 128 KB (16x2048)
    unsigned short* a_bf = (unsigned short*)(ws + 8192 + 131072);   // 512 KB
    unsigned short* n_bf = (unsigned short*)(ws + 8192 + 131072 + 524288); // 8 MB

    prep<<<1280, 256, 0, stream>>>(anchor, positive, negative, a_bf, n_bf,
                                   pos_sim, out);
    fused_gemm_lse<<<512, 256, 0, stream>>>(a_bf, n_bf, partial);
    finalize<<<8, 256, 0, stream>>>(partial, pos_sim, r_score, out);
}

// Round 7
// 99.575 us; speedup vs baseline: 1.2844x; 1.1046x over previous
//
#include <hip/hip_runtime.h>
#include <hip/hip_bf16.h>

// SoftmaxLossRScore: mean(relu(logsumexp(A @ Neg^T, axis=1) - rowdot(A,P) + r + 1))
// B=2048, N=32768, D=128. bf16 MFMA fused GEMM+sumexp, no [B,N] materialization.
// A pre-scaled by log2(e) so epilogue is a bare v_exp_f32 (exp2).
// R7: pinned-A regs (128 rows, af[8][4]) + wave-private LDS-DMA B streaming.
// No __syncthreads in K-loop (each wave stages its own B strip; per-wave
// s_waitcnt vmcnt(8) double-buffer). XOR-swizzled staging keeps ds_read_b128
// at free 2-way conflicts. cc-major grid -> per-XCD B working set 1 MB
// (L2-resident); total B stream 134 MB ~= 3.9us of L2 BW (binding pipe).

#define B_ROWS 2048
#define N_NEG  32768
#define DIM    128
#define LOG2E  1.4426950408889634f
#define LN2    0.6931471805599453f

typedef __bf16 bf16x8 __attribute__((ext_vector_type(8)));
typedef float  f32x4  __attribute__((ext_vector_type(4)));

static __device__ inline unsigned short f2bf(float f) {
    union { float f; unsigned u; } v; v.f = f;
    unsigned r = v.u + 0x7FFF + ((v.u >> 16) & 1);   // round-to-nearest-even
    return (unsigned short)(r >> 16);
}

// opaque register barrier: forbids rematerialization of the producing load
static __device__ inline void pin(bf16x8& v) {
    f32x4 t = __builtin_bit_cast(f32x4, v);
    asm volatile("" : "+v"(t));
    v = __builtin_bit_cast(bf16x8, t);
}

static __device__ inline void load_lds16(const void* g, void* s) {
    __builtin_amdgcn_global_load_lds(
        (const __attribute__((address_space(1))) void*)g,
        (__attribute__((address_space(3))) void*)s,
        16, 0, 0);
}

// ---------- prep: anchor->bf16*log2e + pos_sim, neg->bf16, zero out ---------
__global__ void prep(const float* __restrict__ anchor,
                     const float* __restrict__ positive,
                     const float* __restrict__ neg,
                     unsigned short* __restrict__ a_bf,
                     unsigned short* __restrict__ n_bf,
                     float* __restrict__ pos_sim,
                     float* __restrict__ out) {
    int t = threadIdx.x;
    if (blockIdx.x < 256) {
        if (blockIdx.x == 0 && t == 0) out[0] = 0.0f;
        int row = blockIdx.x * 8 + (t >> 5);
        int c4  = (t & 31) * 4;
        const float4 a4 = *(const float4*)(anchor   + row * DIM + c4);
        const float4 p4 = *(const float4*)(positive + row * DIM + c4);
        float dot = a4.x * p4.x + a4.y * p4.y + a4.z * p4.z + a4.w * p4.w;
        ushort4 ab;
        ab.x = f2bf(a4.x * LOG2E); ab.y = f2bf(a4.y * LOG2E);
        ab.z = f2bf(a4.z * LOG2E); ab.w = f2bf(a4.w * LOG2E);
        *(ushort4*)(a_bf + row * DIM + c4) = ab;
        #pragma unroll
        for (int m = 1; m <= 16; m <<= 1) dot += __shfl_xor(dot, m, 64);
        if ((t & 31) == 0) pos_sim[row] = dot;
    } else {
        int i = (blockIdx.x - 256) * 256 + t;   // float4 index
        #pragma unroll
        for (int k = 0; k < 4; k++) {
            int idx = i + k * (1024 * 256);
            float4 v = *(const float4*)(neg + (size_t)idx * 4);
            ushort4 o;
            o.x = f2bf(v.x); o.y = f2bf(v.y); o.z = f2bf(v.z); o.w = f2bf(v.w);
            *(ushort4*)(n_bf + (size_t)idx * 4) = o;
        }
    }
}

// ---------- main: pinned-A fused bf16 GEMM + sum(exp2) ----------------------
// Grid 512 = rg (16 groups x 128 rows) x cc (32 chunks x 1024 cols), cc-minor
// -> XCD = cc%8. Block 256 thr = 4 waves; wave w streams cols
// [cc*1024 + w*256, +256) in 8 t-steps of 32 cols through a private 2x8KB
// LDS dbuf. Per t: 8 global_load_lds (next), vmcnt(8), 8 ds_read_b128,
// 64 MFMA (8 indep chains), 64 exp, 64 add. No barriers, no atomics.
// LDS col-strip layout: col c at byte c*256; 16B slot u of col c holds global
// chunk u^(c&7) (XOR swizzle on staging src -> 2-way-free frag reads).
__global__ __launch_bounds__(256, 2) void fused_gemm_lse(
        const unsigned short* __restrict__ A,
        const unsigned short* __restrict__ Nb,
        float* __restrict__ partial) {
    __shared__ unsigned short bbuf[4][2][4096];   // 64 KB: per-wave dbuf
    __shared__ float sLDS[4][128];                // 2 KB

    const int tid  = threadIdx.x;
    const int wave = tid >> 6, lane = tid & 63;
    const int q = lane >> 4, c = lane & 15;
    const int cc = blockIdx.x & 31;
    const int rg = blockIdx.x >> 5;

    // A fragments: 128 rows x 128 k, gathered once (L2-hot), pinned (128 VGPR)
    bf16x8 af[8][4];
    const unsigned short* Ab = A + (size_t)rg * 128 * DIM;
    #pragma unroll
    for (int i = 0; i < 8; i++)
        #pragma unroll
        for (int k = 0; k < 4; k++)
            af[i][k] = *(const bf16x8*)(Ab + (i * 16 + c) * DIM + k * 32 + q * 8);
    #pragma unroll
    for (int i = 0; i < 8; i++)
        #pragma unroll
        for (int k = 0; k < 4; k++)
            pin(af[i][k]);

    // staging src offsets (ushort units): instr i stages cols i*4..+4 of the
    // 32-col tile; lane (q=col-in-quad, c=16B-chunk): col ci = i*4+q,
    // src chunk = c ^ (ci&7). (i*4)&7 is 0 (even i) or 4 (odd i).
    const int off_e = q * DIM + ((c ^ q) << 3);
    const int off_o = q * DIM + ((c ^ (q + 4)) << 3);

    // frag-read byte offsets: col (j*16+c) at byte *256; chunk (k*4+q)^(c&7)
    int rck[4];
    #pragma unroll
    for (int k = 0; k < 4; k++) rck[k] = (((k * 4 + q) ^ (c & 7)) << 4);

    const unsigned short* Bw = Nb + ((size_t)cc * 1024 + wave * 256) * DIM;
    unsigned short* sb0 = &bbuf[wave][0][0];
    unsigned short* sb1 = &bbuf[wave][1][0];

    // prologue: stage tile 0 into buf0
    #pragma unroll
    for (int i = 0; i < 8; i++)
        load_lds16(Bw + i * 512 + ((i & 1) ? off_o : off_e), sb0 + i * 512);

    const f32x4 zero4 = {0.f, 0.f, 0.f, 0.f};
    f32x4 sumacc[8];
    #pragma unroll
    for (int i = 0; i < 8; i++) sumacc[i] = zero4;

    for (int t = 0; t < 8; t++) {
        const unsigned short* cur = (t & 1) ? sb1 : sb0;
        if (t < 7) {
            const unsigned short* Bt = Bw + (size_t)(t + 1) * 32 * DIM;
            unsigned short* nx = (t & 1) ? sb0 : sb1;
            #pragma unroll
            for (int i = 0; i < 8; i++)
                load_lds16(Bt + i * 512 + ((i & 1) ? off_o : off_e), nx + i * 512);
            asm volatile("s_waitcnt vmcnt(8)" ::: "memory");   // tile t landed
        } else {
            asm volatile("s_waitcnt vmcnt(0)" ::: "memory");
        }
        #pragma unroll
        for (int j = 0; j < 2; j++) {
            bf16x8 bf[4];
            #pragma unroll
            for (int k = 0; k < 4; k++)
                bf[k] = *(const bf16x8*)((const char*)cur + (j * 16 + c) * 256 + rck[k]);
            #pragma unroll
            for (int i = 0; i < 8; i++) {
                f32x4 acc = __builtin_amdgcn_mfma_f32_16x16x32_bf16(af[i][0], bf[0], zero4, 0, 0, 0);
                acc = __builtin_amdgcn_mfma_f32_16x16x32_bf16(af[i][1], bf[1], acc, 0, 0, 0);
                acc = __builtin_amdgcn_mfma_f32_16x16x32_bf16(af[i][2], bf[2], acc, 0, 0, 0);
                acc = __builtin_amdgcn_mfma_f32_16x16x32_bf16(af[i][3], bf[3], acc, 0, 0, 0);
                sumacc[i][0] += __builtin_amdgcn_exp2f(acc[0]);
                sumacc[i][1] += __builtin_amdgcn_exp2f(acc[1]);
                sumacc[i][2] += __builtin_amdgcn_exp2f(acc[2]);
                sumacc[i][3] += __builtin_amdgcn_exp2f(acc[3]);
            }
        }
    }

    // one-time reduce over the 16 col-lanes; cross-wave combine via LDS
    #pragma unroll
    for (int i = 0; i < 8; i++) {
        #pragma unroll
        for (int r = 0; r < 4; r++) {
            float v = sumacc[i][r];
            v += __shfl_xor(v, 1, 64);
            v += __shfl_xor(v, 2, 64);
            v += __shfl_xor(v, 4, 64);
            v += __shfl_xor(v, 8, 64);
            sumacc[i][r] = v;
        }
        if (c == 0)
            *(f32x4*)&sLDS[wave][i * 16 + q * 4] = sumacc[i];
    }
    __syncthreads();
    if (tid < 128) {
        float s = sLDS[0][tid] + sLDS[1][tid] + sLDS[2][tid] + sLDS[3][tid];
        partial[cc * 2048 + rg * 128 + tid] = s;
    }
}

// ---------- finalize: sum 32 partials/row, lse, relu, mean ------------------
__global__ void finalize(const float* __restrict__ partial,
                         const float* __restrict__ pos_sim,
                         const float* __restrict__ r_score,
                         float* __restrict__ out) {
    __shared__ float red[4];
    const int tid  = threadIdx.x;
    const int wave = tid >> 6, lane = tid & 63;
    const int row  = blockIdx.x * 256 + tid;

    float se = 0.0f;
    #pragma unroll
    for (int ccp = 0; ccp < 32; ccp++)
        se += partial[ccp * 2048 + row];
    float loss = __log2f(se) * LN2 - pos_sim[row] + r_score[row] + 1.0f;
    float acc  = fmaxf(loss, 0.0f);
    #pragma unroll
    for (int m = 1; m <= 32; m <<= 1) acc += __shfl_xor(acc, m, 64);
    if (lane == 0) red[wave] = acc;
    __syncthreads();
    if (tid == 0)
        atomicAdd(out, (red[0] + red[1] + red[2] + red[3]) * (1.0f / (float)B_ROWS));
}

extern "C" void kernel_launch(void* const* d_in, const int* in_sizes, int n_in,
                              void* d_out, int out_size, void* d_ws, size_t ws_size,
                              hipStream_t stream) {
    const float* anchor   = (const float*)d_in[0];
    const float* positive = (const float*)d_in[1];
    const float* negative = (const float*)d_in[2];
    const float* r_score  = (const float*)d_in[3];
    float* out = (float*)d_out;

    char* ws = (char*)d_ws;
    float* pos_sim       = (float*)ws;                              // 8 KB
    float* partial       = (float*)(ws + 8192);                     // 256 KB (32x2048)
    unsigned short* a_bf = (unsigned short*)(ws + 8192 + 262144);   // 512 KB
    unsigned short* n_bf = (unsigned short*)(ws + 8192 + 262144 + 524288); // 8 MB

    prep<<<1280, 256, 0, stream>>>(anchor, positive, negative, a_bf, n_bf,
                                   pos_sim, out);
    fused_gemm_lse<<<512, 256, 0, stream>>>(a_bf, n_bf, partial);
    finalize<<<8, 256, 0, stream>>>(partial, pos_sim, r_score, out);
}